// Round 8
// baseline (839.852 us; speedup 1.0000x reference)
//
#include <hip/hip_runtime.h>
#include <hip/hip_fp16.h>
#include <math.h>

#define Q 8
#define TPB 256
#define WPB (TPB / 64)     // waves per block
#define SCAN_T 1024

struct alignas(16) H8 { __half h[8]; };

// ---------- helpers ----------

__device__ __forceinline__ float fast_rcp(float x) {
  return __builtin_amdgcn_rcpf(x);
}

__device__ __forceinline__ void load8(const float* __restrict__ p, float r[Q]) {
  const float4* p4 = reinterpret_cast<const float4*>(p);
  float4 a = p4[0], b = p4[1];
  r[0]=a.x; r[1]=a.y; r[2]=a.z; r[3]=a.w;
  r[4]=b.x; r[5]=b.y; r[6]=b.z; r[7]=b.w;
}

__device__ __forceinline__ float wave_sum(float x) {
  x += __shfl_down(x, 32);
  x += __shfl_down(x, 16);
  x += __shfl_down(x, 8);
  x += __shfl_down(x, 4);
  x += __shfl_down(x, 2);
  x += __shfl_down(x, 1);
  return x;
}

__device__ __forceinline__ void block_reduce_atomic(float x, float* target, float* lds) {
  float w = wave_sum(x);
  const int lane = threadIdx.x & 63, wid = threadIdx.x >> 6;
  if (lane == 0) lds[wid] = w;
  __syncthreads();
  if (threadIdx.x == 0) {
    float t = 0.f;
#pragma unroll
    for (int i = 0; i < WPB; i++) t += lds[i];
    atomicAdd(target, t);
  }
  __syncthreads();
}

__device__ __forceinline__ float sum8_lanes(float x) {
  x += __shfl_xor(x, 1);
  x += __shfl_xor(x, 2);
  x += __shfl_xor(x, 4);
  return x;
}

// ---------- CSR build ----------

// count + local rank; 8 edges per thread for atomic ILP
__global__ void k_count_pos(const int* __restrict__ dst, int* __restrict__ cnt,
                            int* __restrict__ pos, int E) {
  int i0 = (blockIdx.x * TPB + threadIdx.x) * 8;
  if (i0 + 7 < E) {
    int4 d0 = *reinterpret_cast<const int4*>(dst + i0);
    int4 d1 = *reinterpret_cast<const int4*>(dst + i0 + 4);
    int p0 = atomicAdd(&cnt[d0.x], 1);
    int p1 = atomicAdd(&cnt[d0.y], 1);
    int p2 = atomicAdd(&cnt[d0.z], 1);
    int p3 = atomicAdd(&cnt[d0.w], 1);
    int p4 = atomicAdd(&cnt[d1.x], 1);
    int p5 = atomicAdd(&cnt[d1.y], 1);
    int p6 = atomicAdd(&cnt[d1.z], 1);
    int p7 = atomicAdd(&cnt[d1.w], 1);
    *reinterpret_cast<int4*>(pos + i0)     = make_int4(p0, p1, p2, p3);
    *reinterpret_cast<int4*>(pos + i0 + 4) = make_int4(p4, p5, p6, p7);
  } else {
    for (int e = i0; e < E; e++) pos[e] = atomicAdd(&cnt[dst[e]], 1);
  }
}

__global__ void k_scan1(const int* __restrict__ cnt, int* __restrict__ row_ptr,
                        int* __restrict__ bsum, int N) {
  __shared__ int lds[SCAN_T];
  const int tid = threadIdx.x;
  const int i = blockIdx.x * SCAN_T + tid;
  int c = (i < N) ? cnt[i] : 0;
  lds[tid] = c;
  __syncthreads();
  for (int off = 1; off < SCAN_T; off <<= 1) {
    int v = (tid >= off) ? lds[tid - off] : 0;
    __syncthreads();
    lds[tid] += v;
    __syncthreads();
  }
  if (i < N) row_ptr[i] = lds[tid] - c;
  if (tid == SCAN_T - 1) bsum[blockIdx.x] = lds[tid];
}

__global__ void k_scan2(const int* __restrict__ bsum, int* __restrict__ boffs,
                        int* __restrict__ row_ptr, int nb, int N) {
  __shared__ int lds[SCAN_T];
  const int tid = threadIdx.x;
  int v = (tid < nb) ? bsum[tid] : 0;
  lds[tid] = v;
  __syncthreads();
  for (int off = 1; off < SCAN_T; off <<= 1) {
    int t = (tid >= off) ? lds[tid - off] : 0;
    __syncthreads();
    lds[tid] += t;
    __syncthreads();
  }
  if (tid < nb) boffs[tid] = lds[tid] - v;
  if (tid == 0) row_ptr[N] = lds[nb - 1];
}

__global__ void k_scan3(int* __restrict__ row_ptr, const int* __restrict__ boffs, int N) {
  int i = blockIdx.x * SCAN_T + threadIdx.x;
  if (i < N) row_ptr[i] += boffs[blockIdx.x];
}

// per edge pair: ONE 8B scattered store per directed edge: {rev CSR pos, edge id}
__global__ void k_build(const int* __restrict__ src, const int* __restrict__ dst,
                        const int* __restrict__ pos, const int* __restrict__ row_ptr,
                        int2* __restrict__ rev_eid, int m) {
  int i = blockIdx.x * TPB + threadIdx.x;
  if (i >= m) return;
  const int u = src[i], v = dst[i];
  const int pu = pos[i] + row_ptr[v];       // edge i   (u -> v): in v's segment
  const int pv = pos[i + m] + row_ptr[u];   // edge i+m (v -> u): in u's segment
  rev_eid[pu] = make_int2(pv, i);
  rev_eid[pv] = make_int2(pu, i + m);
}

// initial T in EDGE order (contiguous): T = 1 + ew*normalize(msg_init)
__global__ void k_init_t0(const float* __restrict__ msg_init,
                          const float* __restrict__ beta,
                          __half* __restrict__ t0e, int E) {
  int e = blockIdx.x * TPB + threadIdx.x;
  if (e >= E) return;
  const float ew = expf(beta[0]) - 1.0f;
  float r[Q];
  load8(msg_init + (size_t)e * Q, r);
  float s = 0.f;
#pragma unroll
  for (int j=0;j<Q;j++) s += r[j];
  float inv = ew / s;
  H8 o;
#pragma unroll
  for (int j=0;j<Q;j++) o.h[j] = __float2half(fmaf(r[j], inv, 1.0f));
  *reinterpret_cast<H8*>(t0e + (size_t)e * Q) = o;
}

// ---------- init ----------

// 8-thread group per node: gather T0 via eid (pipelined), pi0 = prod, emit rev[]
// contiguous, cav0[r] = norm(pi0 / T0[r]).
__global__ void k_pi0cav(const int* __restrict__ row_ptr,
                         const int2* __restrict__ rev_eid,
                         const __half* __restrict__ t0e,
                         int* __restrict__ rev,
                         __half* __restrict__ cav0, float* __restrict__ pi0, int N) {
  const int tid = threadIdx.x;
  const int s = tid & 7;
  const int u = (blockIdx.x * TPB + tid) >> 3;
  if (u >= N) return;
  const int st = row_ptr[u], en = row_ptr[u + 1];
  float prod[Q];
#pragma unroll
  for (int j=0;j<Q;j++) prod[j] = 1.f;

  int r = st + s;
  int2 re; H8 t;
  if (r < en) {
    re = rev_eid[r];
    t = *reinterpret_cast<const H8*>(t0e + (size_t)re.y * Q);
  }
  while (r < en) {
    const int r2 = r + 8;
    const int rp = (r2 < en) ? r2 : r;
    int2 re2 = rev_eid[rp];
    H8 t2 = *reinterpret_cast<const H8*>(t0e + (size_t)re2.y * Q);
    rev[r] = re.x;
#pragma unroll
    for (int j=0;j<Q;j++) prod[j] *= __half2float(t.h[j]);
    r = r2; re = re2; t = t2;
  }
#pragma unroll
  for (int j=0;j<Q;j++) {
    prod[j] *= __shfl_xor(prod[j], 1);
    prod[j] *= __shfl_xor(prod[j], 2);
    prod[j] *= __shfl_xor(prod[j], 4);
  }
  if (s == 0) {
    float4* o = reinterpret_cast<float4*>(pi0 + (size_t)u * Q);
    o[0] = make_float4(prod[0], prod[1], prod[2], prod[3]);
    o[1] = make_float4(prod[4], prod[5], prod[6], prod[7]);
  }
  for (int r2 = st + s; r2 < en; r2 += 8) {
    int2 re2 = rev_eid[r2];                                   // L2-hot
    H8 t2 = *reinterpret_cast<const H8*>(t0e + (size_t)re2.y * Q);  // L1/L2-hot
    float c[Q]; float sm = 0.f;
#pragma unroll
    for (int j=0;j<Q;j++) { c[j] = prod[j] * fast_rcp(__half2float(t2.h[j])); sm += c[j]; }
    float inv = fast_rcp(sm);
    H8 o;
#pragma unroll
    for (int j=0;j<Q;j++) o.h[j] = __float2half(c[j] * inv);
    *reinterpret_cast<H8*>(cav0 + (size_t)r2 * Q) = o;
  }
}

__global__ void k_init_nodes(const float* __restrict__ psi_init,
                             float* __restrict__ S0, int N) {
  __shared__ float lds[WPB];
  int n = blockIdx.x * TPB + threadIdx.x;
  float p[Q];
  if (n < N) {
    load8(psi_init + (size_t)n * Q, p);
    float s = 0.f;
#pragma unroll
    for (int j=0;j<Q;j++) s += p[j];
    float inv = 1.0f / s;
#pragma unroll
    for (int j=0;j<Q;j++) p[j] *= inv;
  } else {
#pragma unroll
    for (int j=0;j<Q;j++) p[j] = 0.f;
  }
#pragma unroll
  for (int j=0;j<Q;j++) {
    block_reduce_atomic(p[j], &S0[j], lds);
  }
}

// ---------- per-iteration kernel (cavity form, pipelined pass 1) ----------
__global__ void k_iter2(const int* __restrict__ row_ptr,
                        const int* __restrict__ rev,
                        const __half* __restrict__ cavIn,
                        __half* __restrict__ cavOut,
                        const float* __restrict__ pi_cur,
                        float* __restrict__ pi_nxt,
                        const float* __restrict__ beta,
                        const float* __restrict__ S,
                        float* __restrict__ S_nxt,
                        float neg_mw, int N, int writeCav) {
  __shared__ float part[WPB][Q];
  const int tid = threadIdx.x;
  const int s = tid & 7;
  const float b  = beta[0];
  const float ew = expf(b) - 1.0f;
  const float hb = neg_mw * b;
  float eh[Q];
#pragma unroll
  for (int j=0;j<Q;j++) eh[j] = expf(hb * S[j]);
  const float ehs = expf(hb * S[s]);
  float sacc = 0.f;

  const int u = (blockIdx.x * TPB + tid) >> 3;
  if (u < N) {
    const int st = row_ptr[u], en = row_ptr[u + 1];
    float prod[Q];
#pragma unroll
    for (int j=0;j<Q;j++) prod[j] = 1.f;

    // pass 1: 2-deep pipelined scattered gather
    int r = st + s;
    H8 c;
    if (r < en) {
      const int rv = rev[r];
      c = *reinterpret_cast<const H8*>(cavIn + (size_t)rv * Q);
    }
    while (r < en) {
      const int r2 = r + 8;
      const int rp = (r2 < en) ? r2 : r;
      const int rv2 = rev[rp];
      H8 c2 = *reinterpret_cast<const H8*>(cavIn + (size_t)rv2 * Q);
      float num[Q]; float sm = 0.f;
#pragma unroll
      for (int j=0;j<Q;j++) { num[j] = eh[j] * __half2float(c.h[j]); sm += num[j]; }
      const float inv = fast_rcp(sm) * ew;
      H8 o;
#pragma unroll
      for (int j=0;j<Q;j++) {
        float tn = fmaf(num[j], inv, 1.0f);
        prod[j] *= tn;
        o.h[j] = __float2half(tn);
      }
      *reinterpret_cast<H8*>(cavOut + (size_t)r * Q) = o;   // scratch T, contiguous
      r = r2; c = c2;
    }
    // pi_{t+1}[u]
#pragma unroll
    for (int j=0;j<Q;j++) {
      prod[j] *= __shfl_xor(prod[j], 1);
      prod[j] *= __shfl_xor(prod[j], 2);
      prod[j] *= __shfl_xor(prod[j], 4);
    }
    if (s == 0) {
      float4* o = reinterpret_cast<float4*>(pi_nxt + (size_t)u * Q);
      o[0] = make_float4(prod[0], prod[1], prod[2], prod[3]);
      o[1] = make_float4(prod[4], prod[5], prod[6], prod[7]);
    }
    // psi_{t+1}[u][s] contribution
    {
      float pn = pi_cur[(size_t)u * Q + s] * ehs;
      float smp = sum8_lanes(pn);
      sacc = pn * fast_rcp(smp);
    }
    // pass 2: cav = norm(pi_{t+1}/T), L1-hot re-read
    if (writeCav) {
      for (int r2 = st + s; r2 < en; r2 += 8) {
        H8 t = *reinterpret_cast<const H8*>(cavOut + (size_t)r2 * Q);
        float c2[Q]; float sm = 0.f;
#pragma unroll
        for (int j=0;j<Q;j++) { c2[j] = prod[j] * fast_rcp(__half2float(t.h[j])); sm += c2[j]; }
        const float inv = fast_rcp(sm);
        H8 o;
#pragma unroll
        for (int j=0;j<Q;j++) o.h[j] = __float2half(c2[j] * inv);
        *reinterpret_cast<H8*>(cavOut + (size_t)r2 * Q) = o;
      }
    }
  }
  // S_nxt reduction
  sacc += __shfl_xor(sacc, 8);
  sacc += __shfl_xor(sacc, 16);
  sacc += __shfl_xor(sacc, 32);
  const int lane = tid & 63, wid = tid >> 6;
  if (lane < Q) part[wid][lane] = sacc;
  __syncthreads();
  if (tid < Q) {
    float tot = 0.f;
#pragma unroll
    for (int w = 0; w < WPB; w++) tot += part[w][tid];
    atomicAdd(&S_nxt[tid], tot);
  }
}

// ---------- finalization ----------

__global__ void k_psi_ent(const float* __restrict__ pi,
                          const float* __restrict__ beta,
                          const float* __restrict__ S,
                          float neg_mw, float* __restrict__ psi,
                          float* __restrict__ H_acc, int N) {
  __shared__ float lds[WPB];
  const int j = threadIdx.x & 7;
  const float eh = expf(neg_mw * beta[0] * S[j]);
  float hacc = 0.f;
  const int g0 = (blockIdx.x * TPB + threadIdx.x) >> 3;
  const int gs = (gridDim.x * TPB) >> 3;
  for (int n = g0; n < N; n += gs) {
    float pn = pi[(size_t)n * Q + j] * eh;
    float p = pn / sum8_lanes(pn);
    psi[(size_t)n * Q + j] = p;
    float el = p * logf(p + 1e-12f);
    el = sum8_lanes(el);
    if (j == 0) hacc += el;
  }
  block_reduce_atomic(hacc, H_acc, lds);
}

__global__ void k_edge_stats(const float* __restrict__ psi,
                             const int* __restrict__ src,
                             const int* __restrict__ dst,
                             float* __restrict__ reg_acc,
                             float* __restrict__ mod_acc,
                             float one_minus_mw, int m) {
  __shared__ float lds1[WPB];
  __shared__ float lds2[WPB];
  float reg = 0.f, mod = 0.f;
  for (int i = blockIdx.x * TPB + threadIdx.x; i < m; i += gridDim.x * TPB) {
    int u = src[i], v = dst[i];
    float pu[Q], pv[Q];
    load8(psi + (size_t)u * Q, pu);
    load8(psi + (size_t)v * Q, pv);
#pragma unroll
    for (int j=0;j<Q;j++) { float d = pu[j] - pv[j]; reg += d * d; }
    int au = 0, av = 0;
    float mu = pu[0], mv = pv[0];
#pragma unroll
    for (int j=1;j<Q;j++) {
      if (pu[j] > mu) { mu = pu[j]; au = j; }
      if (pv[j] > mv) { mv = pv[j]; av = j; }
    }
    if (au == av) mod += one_minus_mw;
  }
  block_reduce_atomic(reg, reg_acc, lds1);
  block_reduce_atomic(mod, mod_acc, lds2);
}

__global__ void k_finalize(const float* __restrict__ H_acc,
                           const float* __restrict__ reg_acc,
                           const float* __restrict__ mod_acc,
                           float* __restrict__ out3,
                           float inv_m, float inv_N, float entc) {
  out3[0] = reg_acc[0] * inv_m;
  out3[1] = (-H_acc[0] * inv_N) * entc;
  out3[2] = mod_acc[0] * inv_m;
}

// ---------- host ----------

extern "C" void kernel_launch(void* const* d_in, const int* in_sizes, int n_in,
                              void* d_out, int out_size, void* d_ws, size_t ws_size,
                              hipStream_t stream) {
  const float* msg_init = (const float*)d_in[0];
  const float* psi_init = (const float*)d_in[1];
  const float* beta     = (const float*)d_in[2];
  const int*   src      = (const int*)d_in[3];
  const int*   dst      = (const int*)d_in[4];

  const int E = in_sizes[3];
  const int m = E / 2;
  const int N = in_sizes[1] / Q;
  const double mean_w = (double)E / ((double)N * (double)N);
  const float  neg_mw = (float)(-mean_w);

  float* out = (float*)d_out;

  // ---- workspace layout ----
  __half* cavA = (__half*)d_ws;                     // E*Q halves
  __half* cavB = cavA + (size_t)E * Q;              // E*Q halves
  __half* t0e  = cavB + (size_t)E * Q;              // E*Q halves (edge-order T0)
  int2*  rev_eid = (int2*)(t0e + (size_t)E * Q);    // E int2
  int*   rev     = (int*)(rev_eid + E);             // E
  int*   pos     = rev + E;                         // E
  int*   row_ptr = pos + E;                         // N+1
  int*   cnt     = row_ptr + (N + 1);               // N
  int*   bsum    = cnt + N;                         // SCAN_T
  int*   boffs   = bsum + SCAN_T;                   // SCAN_T
  float* pi0     = (float*)(boffs + SCAN_T);        // N*Q
  float* pi1     = pi0 + (size_t)N * Q;             // N*Q
  float* S       = pi1 + (size_t)N * Q;             // 11*Q
  float* H_acc   = S + 11 * Q;
  float* reg_acc = H_acc + 1;
  float* mod_acc = H_acc + 2;

  const int gridC = (E + TPB * 8 - 1) / (TPB * 8);
  const int gridE = (E + TPB - 1) / TPB;
  const int gridM = (m + TPB - 1) / TPB;
  const int gridN = (N + TPB - 1) / TPB;
  const int gridG = (N * Q + TPB - 1) / TPB;        // 8-thread group per node
  const int gridS = min(512, gridM);
  const int nb    = (N + SCAN_T - 1) / SCAN_T;

  const float entc  = (float)(4.0 * log(0.5) / log(1.0 / (double)Q));
  const float inv_m = (float)(1.0 / (double)m);
  const float inv_N = (float)(1.0 / (double)N);
  const float omw   = (float)(1.0 - mean_w);

  hipMemsetAsync(cnt, 0, (size_t)N * sizeof(int), stream);
  hipMemsetAsync(S, 0, (size_t)(11 * Q + 3) * sizeof(float), stream);

  // CSR build
  k_count_pos<<<gridC, TPB, 0, stream>>>(dst, cnt, pos, E);
  k_scan1<<<nb, SCAN_T, 0, stream>>>(cnt, row_ptr, bsum, N);
  k_scan2<<<1, SCAN_T, 0, stream>>>(bsum, boffs, row_ptr, nb, N);
  k_scan3<<<nb, SCAN_T, 0, stream>>>(row_ptr, boffs, N);
  k_build<<<gridM, TPB, 0, stream>>>(src, dst, pos, row_ptr, rev_eid, m);
  k_init_t0<<<gridE, TPB, 0, stream>>>(msg_init, beta, t0e, E);
  k_pi0cav<<<gridG, TPB, 0, stream>>>(row_ptr, rev_eid, t0e, rev, cavA, pi0, N);
  k_init_nodes<<<gridN, TPB, 0, stream>>>(psi_init, S, N);

  // 9 fused cavity iterations
  __half* ccur = cavA; __half* cnxt = cavB;
  float*  pcur = pi0;  float*  pnxt = pi1;
  for (int t = 0; t < 9; ++t) {
    k_iter2<<<gridG, TPB, 0, stream>>>(row_ptr, rev, ccur, cnxt, pcur, pnxt,
                                       beta, S + t * Q, S + (t + 1) * Q,
                                       neg_mw, N, (t < 8) ? 1 : 0);
    __half* ch = ccur; ccur = cnxt; cnxt = ch;
    float*  pf = pcur; pcur = pnxt; pnxt = pf;
  }

  // psi_10 = normalize(pi_9 * e^{h_9}), entropy fused
  k_psi_ent<<<gridN, TPB, 0, stream>>>(pcur, beta, S + 9 * Q, neg_mw, out, H_acc, N);
  k_edge_stats<<<gridS, TPB, 0, stream>>>(out, src, dst, reg_acc, mod_acc, omw, m);
  k_finalize<<<1, 1, 0, stream>>>(H_acc, reg_acc, mod_acc, out + (size_t)N * Q,
                                  inv_m, inv_N, entc);
}

// Round 9
// 720.427 us; speedup vs baseline: 1.1658x; 1.1658x over previous
//
#include <hip/hip_runtime.h>
#include <hip/hip_fp16.h>
#include <math.h>

#define Q 8
#define TPB 256
#define WPB (TPB / 64)     // waves per block
#define SCAN_T 1024

struct alignas(16) H8 { __half h[8]; };

// ---------- helpers ----------

__device__ __forceinline__ float fast_rcp(float x) {
  return __builtin_amdgcn_rcpf(x);
}

__device__ __forceinline__ void load8(const float* __restrict__ p, float r[Q]) {
  const float4* p4 = reinterpret_cast<const float4*>(p);
  float4 a = p4[0], b = p4[1];
  r[0]=a.x; r[1]=a.y; r[2]=a.z; r[3]=a.w;
  r[4]=b.x; r[5]=b.y; r[6]=b.z; r[7]=b.w;
}

__device__ __forceinline__ void store8h(__half* __restrict__ p, const float r[Q]) {
  H8 t;
#pragma unroll
  for (int j=0;j<Q;j++) t.h[j] = __float2half(r[j]);
  *reinterpret_cast<H8*>(p) = t;
}

__device__ __forceinline__ float wave_sum(float x) {
  x += __shfl_down(x, 32);
  x += __shfl_down(x, 16);
  x += __shfl_down(x, 8);
  x += __shfl_down(x, 4);
  x += __shfl_down(x, 2);
  x += __shfl_down(x, 1);
  return x;
}

__device__ __forceinline__ void block_reduce_atomic(float x, float* target, float* lds) {
  float w = wave_sum(x);
  const int lane = threadIdx.x & 63, wid = threadIdx.x >> 6;
  if (lane == 0) lds[wid] = w;
  __syncthreads();
  if (threadIdx.x == 0) {
    float t = 0.f;
#pragma unroll
    for (int i = 0; i < WPB; i++) t += lds[i];
    atomicAdd(target, t);
  }
  __syncthreads();
}

__device__ __forceinline__ float sum8_lanes(float x) {
  x += __shfl_xor(x, 1);
  x += __shfl_xor(x, 2);
  x += __shfl_xor(x, 4);
  return x;
}

// ---------- CSR build ----------

// count + local rank; 8 edges per thread for atomic ILP
__global__ void k_count_pos(const int* __restrict__ dst, int* __restrict__ cnt,
                            int* __restrict__ pos, int E) {
  int i0 = (blockIdx.x * TPB + threadIdx.x) * 8;
  if (i0 + 7 < E) {
    int4 d0 = *reinterpret_cast<const int4*>(dst + i0);
    int4 d1 = *reinterpret_cast<const int4*>(dst + i0 + 4);
    int p0 = atomicAdd(&cnt[d0.x], 1);
    int p1 = atomicAdd(&cnt[d0.y], 1);
    int p2 = atomicAdd(&cnt[d0.z], 1);
    int p3 = atomicAdd(&cnt[d0.w], 1);
    int p4 = atomicAdd(&cnt[d1.x], 1);
    int p5 = atomicAdd(&cnt[d1.y], 1);
    int p6 = atomicAdd(&cnt[d1.z], 1);
    int p7 = atomicAdd(&cnt[d1.w], 1);
    *reinterpret_cast<int4*>(pos + i0)     = make_int4(p0, p1, p2, p3);
    *reinterpret_cast<int4*>(pos + i0 + 4) = make_int4(p4, p5, p6, p7);
  } else {
    for (int e = i0; e < E; e++) pos[e] = atomicAdd(&cnt[dst[e]], 1);
  }
}

__global__ void k_scan1(const int* __restrict__ cnt, int* __restrict__ row_ptr,
                        int* __restrict__ bsum, int N) {
  __shared__ int lds[SCAN_T];
  const int tid = threadIdx.x;
  const int i = blockIdx.x * SCAN_T + tid;
  int c = (i < N) ? cnt[i] : 0;
  lds[tid] = c;
  __syncthreads();
  for (int off = 1; off < SCAN_T; off <<= 1) {
    int v = (tid >= off) ? lds[tid - off] : 0;
    __syncthreads();
    lds[tid] += v;
    __syncthreads();
  }
  if (i < N) row_ptr[i] = lds[tid] - c;
  if (tid == SCAN_T - 1) bsum[blockIdx.x] = lds[tid];
}

__global__ void k_scan2(const int* __restrict__ bsum, int* __restrict__ boffs,
                        int* __restrict__ row_ptr, int nb, int N) {
  __shared__ int lds[SCAN_T];
  const int tid = threadIdx.x;
  int v = (tid < nb) ? bsum[tid] : 0;
  lds[tid] = v;
  __syncthreads();
  for (int off = 1; off < SCAN_T; off <<= 1) {
    int t = (tid >= off) ? lds[tid - off] : 0;
    __syncthreads();
    lds[tid] += t;
    __syncthreads();
  }
  if (tid < nb) boffs[tid] = lds[tid] - v;
  if (tid == 0) row_ptr[N] = lds[nb - 1];
}

__global__ void k_scan3(int* __restrict__ row_ptr, const int* __restrict__ boffs, int N) {
  int i = blockIdx.x * SCAN_T + threadIdx.x;
  if (i < N) row_ptr[i] += boffs[blockIdx.x];
}

// per edge pair: rev links (4B scatters) + initial T = 1 + ew*norm(msg) scattered
// into CSR order (into the t0 scratch buffer = cavB).
__global__ void k_build(const int* __restrict__ src, const int* __restrict__ dst,
                        const int* __restrict__ pos, const int* __restrict__ row_ptr,
                        const float* __restrict__ msg_init,
                        const float* __restrict__ beta,
                        int* __restrict__ rev, __half* __restrict__ t0, int m) {
  int i = blockIdx.x * TPB + threadIdx.x;
  if (i >= m) return;
  const float b  = beta[0];
  const float ew = expf(b) - 1.0f;
  const int u = src[i], v = dst[i];
  const int pu = pos[i] + row_ptr[v];       // edge i   (u -> v): in v's segment
  const int pv = pos[i + m] + row_ptr[u];   // edge i+m (v -> u): in u's segment
  rev[pu] = pv;
  rev[pv] = pu;

  float r0[Q], r1[Q];
  load8(msg_init + (size_t)i * Q, r0);
  load8(msg_init + ((size_t)i + (size_t)m) * Q, r1);
  float s0 = 0.f, s1 = 0.f;
#pragma unroll
  for (int j=0;j<Q;j++) { s0 += r0[j]; s1 += r1[j]; }
  float i0 = ew / s0, i1 = ew / s1;
#pragma unroll
  for (int j=0;j<Q;j++) { r0[j] = fmaf(r0[j], i0, 1.0f); r1[j] = fmaf(r1[j], i1, 1.0f); }
  store8h(t0 + (size_t)pu * Q, r0);
  store8h(t0 + (size_t)pv * Q, r1);
}

// ---------- init ----------

// 8-thread group per node: pi0 = prod of T0 over segment (contiguous reads);
// cav0[r] = norm(pi0 / T0[r]).
__global__ void k_pi0cav(const int* __restrict__ row_ptr, const __half* __restrict__ t0,
                         __half* __restrict__ cav0, float* __restrict__ pi0, int N) {
  const int tid = threadIdx.x;
  const int s = tid & 7;
  const int u = (blockIdx.x * TPB + tid) >> 3;
  if (u >= N) return;
  const int st = row_ptr[u], en = row_ptr[u + 1];
  float prod[Q];
#pragma unroll
  for (int j=0;j<Q;j++) prod[j] = 1.f;
  for (int r = st + s; r < en; r += 8) {
    H8 t = *reinterpret_cast<const H8*>(t0 + (size_t)r * Q);
#pragma unroll
    for (int j=0;j<Q;j++) prod[j] *= __half2float(t.h[j]);
  }
#pragma unroll
  for (int j=0;j<Q;j++) {
    prod[j] *= __shfl_xor(prod[j], 1);
    prod[j] *= __shfl_xor(prod[j], 2);
    prod[j] *= __shfl_xor(prod[j], 4);
  }
  if (s == 0) {
    float4* o = reinterpret_cast<float4*>(pi0 + (size_t)u * Q);
    o[0] = make_float4(prod[0], prod[1], prod[2], prod[3]);
    o[1] = make_float4(prod[4], prod[5], prod[6], prod[7]);
  }
  for (int r = st + s; r < en; r += 8) {
    H8 t = *reinterpret_cast<const H8*>(t0 + (size_t)r * Q);
    float c[Q]; float sm = 0.f;
#pragma unroll
    for (int j=0;j<Q;j++) { c[j] = prod[j] * fast_rcp(__half2float(t.h[j])); sm += c[j]; }
    float inv = fast_rcp(sm);
    H8 o;
#pragma unroll
    for (int j=0;j<Q;j++) o.h[j] = __float2half(c[j] * inv);
    *reinterpret_cast<H8*>(cav0 + (size_t)r * Q) = o;
  }
}

__global__ void k_init_nodes(const float* __restrict__ psi_init,
                             float* __restrict__ S0, int N) {
  __shared__ float lds[WPB];
  int n = blockIdx.x * TPB + threadIdx.x;
  float p[Q];
  if (n < N) {
    load8(psi_init + (size_t)n * Q, p);
    float s = 0.f;
#pragma unroll
    for (int j=0;j<Q;j++) s += p[j];
    float inv = 1.0f / s;
#pragma unroll
    for (int j=0;j<Q;j++) p[j] *= inv;
  } else {
#pragma unroll
    for (int j=0;j<Q;j++) p[j] = 0.f;
  }
#pragma unroll
  for (int j=0;j<Q;j++) {
    block_reduce_atomic(p[j], &S0[j], lds);
  }
}

// ---------- per-iteration kernel (cavity form, 4-deep batched gather) ----------
// 8-thread group per node u; thread = row-slot, full 8-component row in regs.
// Pass 1 issues up to 4 independent scattered 16B cav reads before consuming.
__global__ void k_iter2(const int* __restrict__ row_ptr,
                        const int* __restrict__ rev,
                        const __half* __restrict__ cavIn,
                        __half* __restrict__ cavOut,
                        const float* __restrict__ pi_cur,
                        float* __restrict__ pi_nxt,
                        const float* __restrict__ beta,
                        const float* __restrict__ S,
                        float* __restrict__ S_nxt,
                        float neg_mw, int N, int writeCav) {
  __shared__ float part[WPB][Q];
  const int tid = threadIdx.x;
  const int s = tid & 7;
  const float b  = beta[0];
  const float ew = expf(b) - 1.0f;
  const float hb = neg_mw * b;
  float eh[Q];
#pragma unroll
  for (int j=0;j<Q;j++) eh[j] = expf(hb * S[j]);
  const float ehs = expf(hb * S[s]);
  float sacc = 0.f;

  const int u = (blockIdx.x * TPB + tid) >> 3;
  if (u < N) {
    const int st = row_ptr[u], en = row_ptr[u + 1];
    float prod[Q];
#pragma unroll
    for (int j=0;j<Q;j++) prod[j] = 1.f;

    // pass 1: batch 4 rows; issue all scattered loads before any consume
    for (int r = st + s; r < en; r += 32) {
      H8 c0, c1, c2, c3;
      const bool ok1 = (r + 8)  < en;
      const bool ok2 = (r + 16) < en;
      const bool ok3 = (r + 24) < en;
      { const int rv = rev[r];
        c0 = *reinterpret_cast<const H8*>(cavIn + (size_t)rv * Q); }
      if (ok1) { const int rv = rev[r + 8];
        c1 = *reinterpret_cast<const H8*>(cavIn + (size_t)rv * Q); }
      if (ok2) { const int rv = rev[r + 16];
        c2 = *reinterpret_cast<const H8*>(cavIn + (size_t)rv * Q); }
      if (ok3) { const int rv = rev[r + 24];
        c3 = *reinterpret_cast<const H8*>(cavIn + (size_t)rv * Q); }

      {
        float num[Q]; float sm = 0.f;
#pragma unroll
        for (int j=0;j<Q;j++) { num[j] = eh[j] * __half2float(c0.h[j]); sm += num[j]; }
        const float inv = fast_rcp(sm) * ew;
        H8 o;
#pragma unroll
        for (int j=0;j<Q;j++) { float tn = fmaf(num[j], inv, 1.0f); prod[j] *= tn; o.h[j] = __float2half(tn); }
        *reinterpret_cast<H8*>(cavOut + (size_t)r * Q) = o;
      }
      if (ok1) {
        float num[Q]; float sm = 0.f;
#pragma unroll
        for (int j=0;j<Q;j++) { num[j] = eh[j] * __half2float(c1.h[j]); sm += num[j]; }
        const float inv = fast_rcp(sm) * ew;
        H8 o;
#pragma unroll
        for (int j=0;j<Q;j++) { float tn = fmaf(num[j], inv, 1.0f); prod[j] *= tn; o.h[j] = __float2half(tn); }
        *reinterpret_cast<H8*>(cavOut + ((size_t)r + 8) * Q) = o;
      }
      if (ok2) {
        float num[Q]; float sm = 0.f;
#pragma unroll
        for (int j=0;j<Q;j++) { num[j] = eh[j] * __half2float(c2.h[j]); sm += num[j]; }
        const float inv = fast_rcp(sm) * ew;
        H8 o;
#pragma unroll
        for (int j=0;j<Q;j++) { float tn = fmaf(num[j], inv, 1.0f); prod[j] *= tn; o.h[j] = __float2half(tn); }
        *reinterpret_cast<H8*>(cavOut + ((size_t)r + 16) * Q) = o;
      }
      if (ok3) {
        float num[Q]; float sm = 0.f;
#pragma unroll
        for (int j=0;j<Q;j++) { num[j] = eh[j] * __half2float(c3.h[j]); sm += num[j]; }
        const float inv = fast_rcp(sm) * ew;
        H8 o;
#pragma unroll
        for (int j=0;j<Q;j++) { float tn = fmaf(num[j], inv, 1.0f); prod[j] *= tn; o.h[j] = __float2half(tn); }
        *reinterpret_cast<H8*>(cavOut + ((size_t)r + 24) * Q) = o;
      }
    }
    // pi_{t+1}[u]
#pragma unroll
    for (int j=0;j<Q;j++) {
      prod[j] *= __shfl_xor(prod[j], 1);
      prod[j] *= __shfl_xor(prod[j], 2);
      prod[j] *= __shfl_xor(prod[j], 4);
    }
    if (s == 0) {
      float4* o = reinterpret_cast<float4*>(pi_nxt + (size_t)u * Q);
      o[0] = make_float4(prod[0], prod[1], prod[2], prod[3]);
      o[1] = make_float4(prod[4], prod[5], prod[6], prod[7]);
    }
    // psi_{t+1}[u][s] contribution
    {
      float pn = pi_cur[(size_t)u * Q + s] * ehs;
      float smp = sum8_lanes(pn);
      sacc = pn * fast_rcp(smp);
    }
    // pass 2: cav = norm(pi_{t+1}/T), L1-hot re-read
    if (writeCav) {
      for (int r2 = st + s; r2 < en; r2 += 8) {
        H8 t = *reinterpret_cast<const H8*>(cavOut + (size_t)r2 * Q);
        float c2[Q]; float sm = 0.f;
#pragma unroll
        for (int j=0;j<Q;j++) { c2[j] = prod[j] * fast_rcp(__half2float(t.h[j])); sm += c2[j]; }
        const float inv = fast_rcp(sm);
        H8 o;
#pragma unroll
        for (int j=0;j<Q;j++) o.h[j] = __float2half(c2[j] * inv);
        *reinterpret_cast<H8*>(cavOut + (size_t)r2 * Q) = o;
      }
    }
  }
  // S_nxt reduction
  sacc += __shfl_xor(sacc, 8);
  sacc += __shfl_xor(sacc, 16);
  sacc += __shfl_xor(sacc, 32);
  const int lane = tid & 63, wid = tid >> 6;
  if (lane < Q) part[wid][lane] = sacc;
  __syncthreads();
  if (tid < Q) {
    float tot = 0.f;
#pragma unroll
    for (int w = 0; w < WPB; w++) tot += part[w][tid];
    atomicAdd(&S_nxt[tid], tot);
  }
}

// ---------- finalization ----------

__global__ void k_psi_ent(const float* __restrict__ pi,
                          const float* __restrict__ beta,
                          const float* __restrict__ S,
                          float neg_mw, float* __restrict__ psi,
                          float* __restrict__ H_acc, int N) {
  __shared__ float lds[WPB];
  const int j = threadIdx.x & 7;
  const float eh = expf(neg_mw * beta[0] * S[j]);
  float hacc = 0.f;
  const int g0 = (blockIdx.x * TPB + threadIdx.x) >> 3;
  const int gs = (gridDim.x * TPB) >> 3;
  for (int n = g0; n < N; n += gs) {
    float pn = pi[(size_t)n * Q + j] * eh;
    float p = pn / sum8_lanes(pn);
    psi[(size_t)n * Q + j] = p;
    float el = p * logf(p + 1e-12f);
    el = sum8_lanes(el);
    if (j == 0) hacc += el;
  }
  block_reduce_atomic(hacc, H_acc, lds);
}

__global__ void k_edge_stats(const float* __restrict__ psi,
                             const int* __restrict__ src,
                             const int* __restrict__ dst,
                             float* __restrict__ reg_acc,
                             float* __restrict__ mod_acc,
                             float one_minus_mw, int m) {
  __shared__ float lds1[WPB];
  __shared__ float lds2[WPB];
  float reg = 0.f, mod = 0.f;
  for (int i = blockIdx.x * TPB + threadIdx.x; i < m; i += gridDim.x * TPB) {
    int u = src[i], v = dst[i];
    float pu[Q], pv[Q];
    load8(psi + (size_t)u * Q, pu);
    load8(psi + (size_t)v * Q, pv);
#pragma unroll
    for (int j=0;j<Q;j++) { float d = pu[j] - pv[j]; reg += d * d; }
    int au = 0, av = 0;
    float mu = pu[0], mv = pv[0];
#pragma unroll
    for (int j=1;j<Q;j++) {
      if (pu[j] > mu) { mu = pu[j]; au = j; }
      if (pv[j] > mv) { mv = pv[j]; av = j; }
    }
    if (au == av) mod += one_minus_mw;
  }
  block_reduce_atomic(reg, reg_acc, lds1);
  block_reduce_atomic(mod, mod_acc, lds2);
}

__global__ void k_finalize(const float* __restrict__ H_acc,
                           const float* __restrict__ reg_acc,
                           const float* __restrict__ mod_acc,
                           float* __restrict__ out3,
                           float inv_m, float inv_N, float entc) {
  out3[0] = reg_acc[0] * inv_m;
  out3[1] = (-H_acc[0] * inv_N) * entc;
  out3[2] = mod_acc[0] * inv_m;
}

// ---------- host ----------

extern "C" void kernel_launch(void* const* d_in, const int* in_sizes, int n_in,
                              void* d_out, int out_size, void* d_ws, size_t ws_size,
                              hipStream_t stream) {
  const float* msg_init = (const float*)d_in[0];
  const float* psi_init = (const float*)d_in[1];
  const float* beta     = (const float*)d_in[2];
  const int*   src      = (const int*)d_in[3];
  const int*   dst      = (const int*)d_in[4];

  const int E = in_sizes[3];
  const int m = E / 2;
  const int N = in_sizes[1] / Q;
  const double mean_w = (double)E / ((double)N * (double)N);
  const float  neg_mw = (float)(-mean_w);

  float* out = (float*)d_out;

  // ---- workspace layout ----
  __half* cavA = (__half*)d_ws;                     // E*Q halves
  __half* cavB = cavA + (size_t)E * Q;              // E*Q halves (t0 scratch first)
  int*   rev     = (int*)(cavB + (size_t)E * Q);    // E
  int*   pos     = rev + E;                         // E
  int*   row_ptr = pos + E;                         // N+1
  int*   cnt     = row_ptr + (N + 1);               // N
  int*   bsum    = cnt + N;                         // SCAN_T
  int*   boffs   = bsum + SCAN_T;                   // SCAN_T
  float* pi0     = (float*)(boffs + SCAN_T);        // N*Q
  float* pi1     = pi0 + (size_t)N * Q;             // N*Q
  float* S       = pi1 + (size_t)N * Q;             // 11*Q
  float* H_acc   = S + 11 * Q;
  float* reg_acc = H_acc + 1;
  float* mod_acc = H_acc + 2;

  const int gridC = (E + TPB * 8 - 1) / (TPB * 8);
  const int gridM = (m + TPB - 1) / TPB;
  const int gridN = (N + TPB - 1) / TPB;
  const int gridG = (N * Q + TPB - 1) / TPB;        // 8-thread group per node
  const int gridS = min(512, gridM);
  const int nb    = (N + SCAN_T - 1) / SCAN_T;

  const float entc  = (float)(4.0 * log(0.5) / log(1.0 / (double)Q));
  const float inv_m = (float)(1.0 / (double)m);
  const float inv_N = (float)(1.0 / (double)N);
  const float omw   = (float)(1.0 - mean_w);

  hipMemsetAsync(cnt, 0, (size_t)N * sizeof(int), stream);
  hipMemsetAsync(S, 0, (size_t)(11 * Q + 3) * sizeof(float), stream);

  // CSR build
  k_count_pos<<<gridC, TPB, 0, stream>>>(dst, cnt, pos, E);
  k_scan1<<<nb, SCAN_T, 0, stream>>>(cnt, row_ptr, bsum, N);
  k_scan2<<<1, SCAN_T, 0, stream>>>(bsum, boffs, row_ptr, nb, N);
  k_scan3<<<nb, SCAN_T, 0, stream>>>(row_ptr, boffs, N);
  k_build<<<gridM, TPB, 0, stream>>>(src, dst, pos, row_ptr, msg_init, beta,
                                     rev, cavB, m);
  k_pi0cav<<<gridG, TPB, 0, stream>>>(row_ptr, cavB, cavA, pi0, N);
  k_init_nodes<<<gridN, TPB, 0, stream>>>(psi_init, S, N);

  // 9 fused cavity iterations
  __half* ccur = cavA; __half* cnxt = cavB;
  float*  pcur = pi0;  float*  pnxt = pi1;
  for (int t = 0; t < 9; ++t) {
    k_iter2<<<gridG, TPB, 0, stream>>>(row_ptr, rev, ccur, cnxt, pcur, pnxt,
                                       beta, S + t * Q, S + (t + 1) * Q,
                                       neg_mw, N, (t < 8) ? 1 : 0);
    __half* ch = ccur; ccur = cnxt; cnxt = ch;
    float*  pf = pcur; pcur = pnxt; pnxt = pf;
  }

  // psi_10 = normalize(pi_9 * e^{h_9}), entropy fused
  k_psi_ent<<<gridN, TPB, 0, stream>>>(pcur, beta, S + 9 * Q, neg_mw, out, H_acc, N);
  k_edge_stats<<<gridS, TPB, 0, stream>>>(out, src, dst, reg_acc, mod_acc, omw, m);
  k_finalize<<<1, 1, 0, stream>>>(H_acc, reg_acc, mod_acc, out + (size_t)N * Q,
                                  inv_m, inv_N, entc);
}

// Round 10
// 697.677 us; speedup vs baseline: 1.2038x; 1.0326x over previous
//
#include <hip/hip_runtime.h>
#include <hip/hip_fp16.h>
#include <math.h>

#define Q 8
#define TPB 256
#define WPB (TPB / 64)     // waves per block
#define SCAN_T 1024

struct alignas(16) H8 { __half h[8]; };

// ---------- helpers ----------

__device__ __forceinline__ float fast_rcp(float x) {
  return __builtin_amdgcn_rcpf(x);
}

__device__ __forceinline__ void load8(const float* __restrict__ p, float r[Q]) {
  const float4* p4 = reinterpret_cast<const float4*>(p);
  float4 a = p4[0], b = p4[1];
  r[0]=a.x; r[1]=a.y; r[2]=a.z; r[3]=a.w;
  r[4]=b.x; r[5]=b.y; r[6]=b.z; r[7]=b.w;
}

__device__ __forceinline__ void store8h(__half* __restrict__ p, const float r[Q]) {
  H8 t;
#pragma unroll
  for (int j=0;j<Q;j++) t.h[j] = __float2half(r[j]);
  *reinterpret_cast<H8*>(p) = t;
}

__device__ __forceinline__ float wave_sum(float x) {
  x += __shfl_down(x, 32);
  x += __shfl_down(x, 16);
  x += __shfl_down(x, 8);
  x += __shfl_down(x, 4);
  x += __shfl_down(x, 2);
  x += __shfl_down(x, 1);
  return x;
}

__device__ __forceinline__ void block_reduce_atomic(float x, float* target, float* lds) {
  float w = wave_sum(x);
  const int lane = threadIdx.x & 63, wid = threadIdx.x >> 6;
  if (lane == 0) lds[wid] = w;
  __syncthreads();
  if (threadIdx.x == 0) {
    float t = 0.f;
#pragma unroll
    for (int i = 0; i < WPB; i++) t += lds[i];
    atomicAdd(target, t);
  }
  __syncthreads();
}

__device__ __forceinline__ float sum8_lanes(float x) {
  x += __shfl_xor(x, 1);
  x += __shfl_xor(x, 2);
  x += __shfl_xor(x, 4);
  return x;
}

// ---------- CSR build ----------

// count + local rank; 4 edges per thread (measured-best variant)
__global__ void k_count_pos(const int* __restrict__ dst, int* __restrict__ cnt,
                            int* __restrict__ pos, int E) {
  int i0 = (blockIdx.x * TPB + threadIdx.x) * 4;
  if (i0 + 3 < E) {
    int4 d = *reinterpret_cast<const int4*>(dst + i0);
    int p0 = atomicAdd(&cnt[d.x], 1);
    int p1 = atomicAdd(&cnt[d.y], 1);
    int p2 = atomicAdd(&cnt[d.z], 1);
    int p3 = atomicAdd(&cnt[d.w], 1);
    *reinterpret_cast<int4*>(pos + i0) = make_int4(p0, p1, p2, p3);
  } else {
    for (int e = i0; e < E; e++) pos[e] = atomicAdd(&cnt[dst[e]], 1);
  }
}

__global__ void k_scan1(const int* __restrict__ cnt, int* __restrict__ row_ptr,
                        int* __restrict__ bsum, int N) {
  __shared__ int lds[SCAN_T];
  const int tid = threadIdx.x;
  const int i = blockIdx.x * SCAN_T + tid;
  int c = (i < N) ? cnt[i] : 0;
  lds[tid] = c;
  __syncthreads();
  for (int off = 1; off < SCAN_T; off <<= 1) {
    int v = (tid >= off) ? lds[tid - off] : 0;
    __syncthreads();
    lds[tid] += v;
    __syncthreads();
  }
  if (i < N) row_ptr[i] = lds[tid] - c;
  if (tid == SCAN_T - 1) bsum[blockIdx.x] = lds[tid];
}

__global__ void k_scan2(const int* __restrict__ bsum, int* __restrict__ boffs,
                        int* __restrict__ row_ptr, int nb, int N) {
  __shared__ int lds[SCAN_T];
  const int tid = threadIdx.x;
  int v = (tid < nb) ? bsum[tid] : 0;
  lds[tid] = v;
  __syncthreads();
  for (int off = 1; off < SCAN_T; off <<= 1) {
    int t = (tid >= off) ? lds[tid - off] : 0;
    __syncthreads();
    lds[tid] += t;
    __syncthreads();
  }
  if (tid < nb) boffs[tid] = lds[tid] - v;
  if (tid == 0) row_ptr[N] = lds[nb - 1];
}

__global__ void k_scan3(int* __restrict__ row_ptr, const int* __restrict__ boffs, int N) {
  int i = blockIdx.x * SCAN_T + threadIdx.x;
  if (i < N) row_ptr[i] += boffs[blockIdx.x];
}

// per edge pair: rn = {rev CSR pos, neighbor} (8B) + initial T (16B) scattered
// into CSR order.
__global__ void k_build(const int* __restrict__ src, const int* __restrict__ dst,
                        const int* __restrict__ pos, const int* __restrict__ row_ptr,
                        const float* __restrict__ msg_init,
                        const float* __restrict__ beta,
                        int2* __restrict__ rn, __half* __restrict__ t0, int m) {
  int i = blockIdx.x * TPB + threadIdx.x;
  if (i >= m) return;
  const float b  = beta[0];
  const float ew = expf(b) - 1.0f;
  const int u = src[i], v = dst[i];
  const int pu = pos[i] + row_ptr[v];       // edge i   (u -> v): in v's segment
  const int pv = pos[i + m] + row_ptr[u];   // edge i+m (v -> u): in u's segment
  rn[pu] = make_int2(pv, u);
  rn[pv] = make_int2(pu, v);

  float r0[Q], r1[Q];
  load8(msg_init + (size_t)i * Q, r0);
  load8(msg_init + ((size_t)i + (size_t)m) * Q, r1);
  float s0 = 0.f, s1 = 0.f;
#pragma unroll
  for (int j=0;j<Q;j++) { s0 += r0[j]; s1 += r1[j]; }
  float i0 = ew / s0, i1 = ew / s1;
#pragma unroll
  for (int j=0;j<Q;j++) { r0[j] = fmaf(r0[j], i0, 1.0f); r1[j] = fmaf(r1[j], i1, 1.0f); }
  store8h(t0 + (size_t)pu * Q, r0);
  store8h(t0 + (size_t)pv * Q, r1);
}

// ---------- init ----------

// 8-thread group per node: pi0 = prod of T0 over segment (contiguous reads)
__global__ void k_pi0(const int* __restrict__ row_ptr, const __half* __restrict__ t0,
                      float* __restrict__ pi0, int N) {
  const int tid = threadIdx.x;
  const int s = tid & 7;
  const int u = (blockIdx.x * TPB + tid) >> 3;
  if (u >= N) return;
  const int st = row_ptr[u], en = row_ptr[u + 1];
  float prod[Q];
#pragma unroll
  for (int j=0;j<Q;j++) prod[j] = 1.f;
  for (int r = st + s; r < en; r += 8) {
    H8 t = *reinterpret_cast<const H8*>(t0 + (size_t)r * Q);
#pragma unroll
    for (int j=0;j<Q;j++) prod[j] *= __half2float(t.h[j]);
  }
#pragma unroll
  for (int j=0;j<Q;j++) {
    prod[j] *= __shfl_xor(prod[j], 1);
    prod[j] *= __shfl_xor(prod[j], 2);
    prod[j] *= __shfl_xor(prod[j], 4);
  }
  if (s == 0) {
    float4* o = reinterpret_cast<float4*>(pi0 + (size_t)u * Q);
    o[0] = make_float4(prod[0], prod[1], prod[2], prod[3]);
    o[1] = make_float4(prod[4], prod[5], prod[6], prod[7]);
  }
}

__global__ void k_init_nodes(const float* __restrict__ psi_init,
                             float* __restrict__ S0, int N) {
  __shared__ float lds[WPB];
  int n = blockIdx.x * TPB + threadIdx.x;
  float p[Q];
  if (n < N) {
    load8(psi_init + (size_t)n * Q, p);
    float s = 0.f;
#pragma unroll
    for (int j=0;j<Q;j++) s += p[j];
    float inv = 1.0f / s;
#pragma unroll
    for (int j=0;j<Q;j++) p[j] *= inv;
  } else {
#pragma unroll
    for (int j=0;j<Q;j++) p[j] = 0.f;
  }
#pragma unroll
  for (int j=0;j<Q;j++) {
    block_reduce_atomic(p[j], &S0[j], lds);
  }
}

// ---------- per-iteration kernel (deferred-normalization, single pass) ----------
// 8-thread group per node u; thread = row-slot, full 8-component row in regs.
// Row r in seg(u) (edge v->u), rn[r] = {rev, v}:
//   num[j] = eh[j] * pi_t[v][j] / T_t[rev][j]      (pi gather is L2-resident)
//   msg    = num / sum_j num                        (in-thread normalize)
//   T_{t+1}[r][j] = 1 + ew*msg[j]                   (contiguous fp16 write)
//   pi_{t+1}[u] = prod of T_{t+1} over segment      (register + shuffle product)
//   psi_{t+1}[u] = norm(pi_t[u]*eh) -> S_nxt        (block-reduced)
__global__ void k_iter3(const int* __restrict__ row_ptr,
                        const int2* __restrict__ rn,
                        const __half* __restrict__ tIn,
                        __half* __restrict__ tOut,
                        const float* __restrict__ pi_cur,
                        float* __restrict__ pi_nxt,
                        const float* __restrict__ beta,
                        const float* __restrict__ S,
                        float* __restrict__ S_nxt,
                        float neg_mw, int N, int writeT) {
  __shared__ float part[WPB][Q];
  const int tid = threadIdx.x;
  const int s = tid & 7;
  const float b  = beta[0];
  const float ew = expf(b) - 1.0f;
  const float hb = neg_mw * b;
  float eh[Q];
#pragma unroll
  for (int j=0;j<Q;j++) eh[j] = expf(hb * S[j]);
  const float ehs = expf(hb * S[s]);
  float sacc = 0.f;

  const int u = (blockIdx.x * TPB + tid) >> 3;
  if (u < N) {
    const int st = row_ptr[u], en = row_ptr[u + 1];
    float prod[Q];
#pragma unroll
    for (int j=0;j<Q;j++) prod[j] = 1.f;

    // 2-deep pipelined gather: T[rev] scattered 16B + pi[v] 32B (L2-resident)
    int r = st + s;
    H8 c; float4 pa, pb;
    if (r < en) {
      const int2 w = rn[r];
      c  = *reinterpret_cast<const H8*>(tIn + (size_t)w.x * Q);
      const float4* pp = reinterpret_cast<const float4*>(pi_cur + (size_t)w.y * Q);
      pa = pp[0]; pb = pp[1];
    }
    while (r < en) {
      const int r2 = r + 8;
      H8 c2; float4 pa2, pb2;
      if (r2 < en) {
        const int2 w2 = rn[r2];
        c2 = *reinterpret_cast<const H8*>(tIn + (size_t)w2.x * Q);
        const float4* pp2 = reinterpret_cast<const float4*>(pi_cur + (size_t)w2.y * Q);
        pa2 = pp2[0]; pb2 = pp2[1];
      }
      float pv[Q];
      pv[0]=pa.x; pv[1]=pa.y; pv[2]=pa.z; pv[3]=pa.w;
      pv[4]=pb.x; pv[5]=pb.y; pv[6]=pb.z; pv[7]=pb.w;
      float num[Q]; float sm = 0.f;
#pragma unroll
      for (int j=0;j<Q;j++) {
        num[j] = eh[j] * pv[j] * fast_rcp(__half2float(c.h[j]));
        sm += num[j];
      }
      const float inv = fast_rcp(sm) * ew;
      H8 o;
#pragma unroll
      for (int j=0;j<Q;j++) {
        float tn = fmaf(num[j], inv, 1.0f);
        prod[j] *= tn;
        o.h[j] = __float2half(tn);
      }
      if (writeT) *reinterpret_cast<H8*>(tOut + (size_t)r * Q) = o;
      r = r2; c = c2; pa = pa2; pb = pb2;
    }
    // pi_{t+1}[u]: elementwise product across the 8 slot threads
#pragma unroll
    for (int j=0;j<Q;j++) {
      prod[j] *= __shfl_xor(prod[j], 1);
      prod[j] *= __shfl_xor(prod[j], 2);
      prod[j] *= __shfl_xor(prod[j], 4);
    }
    if (s == 0) {
      float4* o = reinterpret_cast<float4*>(pi_nxt + (size_t)u * Q);
      o[0] = make_float4(prod[0], prod[1], prod[2], prod[3]);
      o[1] = make_float4(prod[4], prod[5], prod[6], prod[7]);
    }
    // psi_{t+1}[u][s] contribution (thread s owns component s)
    {
      float pn = pi_cur[(size_t)u * Q + s] * ehs;
      float smp = sum8_lanes(pn);
      sacc = pn * fast_rcp(smp);
    }
  }
  // S_nxt reduction
  sacc += __shfl_xor(sacc, 8);
  sacc += __shfl_xor(sacc, 16);
  sacc += __shfl_xor(sacc, 32);
  const int lane = tid & 63, wid = tid >> 6;
  if (lane < Q) part[wid][lane] = sacc;
  __syncthreads();
  if (tid < Q) {
    float tot = 0.f;
#pragma unroll
    for (int w = 0; w < WPB; w++) tot += part[w][tid];
    atomicAdd(&S_nxt[tid], tot);
  }
}

// ---------- finalization ----------

__global__ void k_psi_ent(const float* __restrict__ pi,
                          const float* __restrict__ beta,
                          const float* __restrict__ S,
                          float neg_mw, float* __restrict__ psi,
                          float* __restrict__ H_acc, int N) {
  __shared__ float lds[WPB];
  const int j = threadIdx.x & 7;
  const float eh = expf(neg_mw * beta[0] * S[j]);
  float hacc = 0.f;
  const int g0 = (blockIdx.x * TPB + threadIdx.x) >> 3;
  const int gs = (gridDim.x * TPB) >> 3;
  for (int n = g0; n < N; n += gs) {
    float pn = pi[(size_t)n * Q + j] * eh;
    float p = pn / sum8_lanes(pn);
    psi[(size_t)n * Q + j] = p;
    float el = p * logf(p + 1e-12f);
    el = sum8_lanes(el);
    if (j == 0) hacc += el;
  }
  block_reduce_atomic(hacc, H_acc, lds);
}

__global__ void k_edge_stats(const float* __restrict__ psi,
                             const int* __restrict__ src,
                             const int* __restrict__ dst,
                             float* __restrict__ reg_acc,
                             float* __restrict__ mod_acc,
                             float one_minus_mw, int m) {
  __shared__ float lds1[WPB];
  __shared__ float lds2[WPB];
  float reg = 0.f, mod = 0.f;
  for (int i = blockIdx.x * TPB + threadIdx.x; i < m; i += gridDim.x * TPB) {
    int u = src[i], v = dst[i];
    float pu[Q], pv[Q];
    load8(psi + (size_t)u * Q, pu);
    load8(psi + (size_t)v * Q, pv);
#pragma unroll
    for (int j=0;j<Q;j++) { float d = pu[j] - pv[j]; reg += d * d; }
    int au = 0, av = 0;
    float mu = pu[0], mv = pv[0];
#pragma unroll
    for (int j=1;j<Q;j++) {
      if (pu[j] > mu) { mu = pu[j]; au = j; }
      if (pv[j] > mv) { mv = pv[j]; av = j; }
    }
    if (au == av) mod += one_minus_mw;
  }
  block_reduce_atomic(reg, reg_acc, lds1);
  block_reduce_atomic(mod, mod_acc, lds2);
}

__global__ void k_finalize(const float* __restrict__ H_acc,
                           const float* __restrict__ reg_acc,
                           const float* __restrict__ mod_acc,
                           float* __restrict__ out3,
                           float inv_m, float inv_N, float entc) {
  out3[0] = reg_acc[0] * inv_m;
  out3[1] = (-H_acc[0] * inv_N) * entc;
  out3[2] = mod_acc[0] * inv_m;
}

// ---------- host ----------

extern "C" void kernel_launch(void* const* d_in, const int* in_sizes, int n_in,
                              void* d_out, int out_size, void* d_ws, size_t ws_size,
                              hipStream_t stream) {
  const float* msg_init = (const float*)d_in[0];
  const float* psi_init = (const float*)d_in[1];
  const float* beta     = (const float*)d_in[2];
  const int*   src      = (const int*)d_in[3];
  const int*   dst      = (const int*)d_in[4];

  const int E = in_sizes[3];
  const int m = E / 2;
  const int N = in_sizes[1] / Q;
  const double mean_w = (double)E / ((double)N * (double)N);
  const float  neg_mw = (float)(-mean_w);

  float* out = (float*)d_out;

  // ---- workspace layout ----
  __half* tA = (__half*)d_ws;                       // E*Q halves
  __half* tB = tA + (size_t)E * Q;                  // E*Q halves
  int2*  rn      = (int2*)(tB + (size_t)E * Q);     // E int2
  int*   pos     = (int*)(rn + E);                  // E
  int*   row_ptr = pos + E;                         // N+1
  int*   cnt     = row_ptr + (N + 1);               // N
  int*   bsum    = cnt + N;                         // SCAN_T
  int*   boffs   = bsum + SCAN_T;                   // SCAN_T
  float* pi0     = (float*)(boffs + SCAN_T);        // N*Q
  float* pi1     = pi0 + (size_t)N * Q;             // N*Q
  float* S       = pi1 + (size_t)N * Q;             // 11*Q
  float* H_acc   = S + 11 * Q;
  float* reg_acc = H_acc + 1;
  float* mod_acc = H_acc + 2;

  const int gridC = (E + TPB * 4 - 1) / (TPB * 4);
  const int gridM = (m + TPB - 1) / TPB;
  const int gridN = (N + TPB - 1) / TPB;
  const int gridG = (N * Q + TPB - 1) / TPB;        // 8-thread group per node
  const int gridS = min(512, gridM);
  const int nb    = (N + SCAN_T - 1) / SCAN_T;

  const float entc  = (float)(4.0 * log(0.5) / log(1.0 / (double)Q));
  const float inv_m = (float)(1.0 / (double)m);
  const float inv_N = (float)(1.0 / (double)N);
  const float omw   = (float)(1.0 - mean_w);

  hipMemsetAsync(cnt, 0, (size_t)N * sizeof(int), stream);
  hipMemsetAsync(S, 0, (size_t)(11 * Q + 3) * sizeof(float), stream);

  // CSR build
  k_count_pos<<<gridC, TPB, 0, stream>>>(dst, cnt, pos, E);
  k_scan1<<<nb, SCAN_T, 0, stream>>>(cnt, row_ptr, bsum, N);
  k_scan2<<<1, SCAN_T, 0, stream>>>(bsum, boffs, row_ptr, nb, N);
  k_scan3<<<nb, SCAN_T, 0, stream>>>(row_ptr, boffs, N);
  k_build<<<gridM, TPB, 0, stream>>>(src, dst, pos, row_ptr, msg_init, beta,
                                     rn, tA, m);
  k_pi0<<<gridG, TPB, 0, stream>>>(row_ptr, tA, pi0, N);
  k_init_nodes<<<gridN, TPB, 0, stream>>>(psi_init, S, N);

  // 9 deferred-normalization iterations
  __half* tcur = tA; __half* tnxt = tB;
  float*  pcur = pi0; float* pnxt = pi1;
  for (int t = 0; t < 9; ++t) {
    k_iter3<<<gridG, TPB, 0, stream>>>(row_ptr, rn, tcur, tnxt, pcur, pnxt,
                                       beta, S + t * Q, S + (t + 1) * Q,
                                       neg_mw, N, (t < 8) ? 1 : 0);
    __half* th = tcur; tcur = tnxt; tnxt = th;
    float*  pf = pcur; pcur = pnxt; pnxt = pf;
  }

  // psi_10 = normalize(pi_9 * e^{h_9}), entropy fused
  k_psi_ent<<<gridN, TPB, 0, stream>>>(pcur, beta, S + 9 * Q, neg_mw, out, H_acc, N);
  k_edge_stats<<<gridS, TPB, 0, stream>>>(out, src, dst, reg_acc, mod_acc, omw, m);
  k_finalize<<<1, 1, 0, stream>>>(H_acc, reg_acc, mod_acc, out + (size_t)N * Q,
                                  inv_m, inv_N, entc);
}